// Round 1
// baseline (1459.038 us; speedup 1.0000x reference)
//
#include <hip/hip_runtime.h>
#include <hip/hip_bf16.h>

// B=16, H=W=128, N=16384, DIM=64, HEADS=2, HD=32, MLP_H=256
#define NB 16
#define NT 16384
#define NTOK (NB * NT)

typedef __hip_bfloat16 bf16;

__device__ __forceinline__ float rl(float v, int l) {
    return __int_as_float(__builtin_amdgcn_readlane(__float_as_int(v), l));
}
__device__ __forceinline__ float bf2f(bf16 v) { return __bfloat162float(v); }
__device__ __forceinline__ bf16  f2bf(float v) { return __float2bfloat16(v); }

__device__ __forceinline__ float redsum64(float v) {
    #pragma unroll
    for (int m = 1; m < 64; m <<= 1) v += __shfl_xor(v, m, 64);
    return v;
}

// safe_pow: max(x,0)^p, 0 at 0
__device__ __forceinline__ float safe_pow(float x, float p) {
    return (x > 0.f) ? __expf(p * __logf(x)) : 0.f;
}

// ---------------------------------------------------------------------------
// k1: LN1 + qg/kv projections + k features + per-(b,h) reductions
// grid (64, B), 256 threads. Each block: 256 tokens of batch b.
// ---------------------------------------------------------------------------
__global__ __launch_bounds__(256)
void k1_proj(const float* __restrict__ x,
             const float* __restrict__ ln1_g, const float* __restrict__ ln1_b,
             const float* __restrict__ w_qg, const float* __restrict__ w_kv,
             const float* __restrict__ pos_enc,
             const float* __restrict__ scale_p, const float* __restrict__ power_p,
             bf16* __restrict__ qb, bf16* __restrict__ gbuf, bf16* __restrict__ vbuf,
             float* __restrict__ km_g, float* __restrict__ kv_g)
{
    const int b = blockIdx.y;
    const int chunk = blockIdx.x;
    const int tid = threadIdx.x;
    const int wave = tid >> 6;
    const int c = tid & 63;

    __shared__ float kc2[32][128];  // [tok][pn*64 + c]: pn=0 -> k_pos, 1 -> k_neg
    __shared__ float vs_[32][64];

    const float g1 = ln1_g[c], bb1 = ln1_b[c];
    const float inv_scale = 1.f / log1pf(__expf(scale_p[c]));          // 1/softplus
    const float pw = 1.f + 4.f / (1.f + __expf(-power_p[c]));          // 1+4*sigmoid

    // phase-D ownership: thread -> (s, h, j), owns e=0..15
    const int ds = tid >> 7;          // 0 -> sim (v1), 1 -> opp (v2)
    const int dh = (tid >> 6) & 1;
    const int dj = tid & 63;
    float kvacc[16];
    #pragma unroll
    for (int e = 0; e < 16; e++) kvacc[e] = 0.f;
    float kmacc = 0.f;

    for (int iter = 0; iter < 8; ++iter) {
        const int nbase = chunk * 256 + iter * 32 + wave * 8;
        // LN1 for 8 tokens, h1 register-distributed (lane = channel)
        float h1r[8];
        #pragma unroll
        for (int t = 0; t < 8; t++) {
            size_t idx = (((size_t)b * NT) + nbase + t) * 64 + c;
            float xv = x[idx];
            float s1 = redsum64(xv);
            float s2 = redsum64(xv * xv);
            float mu = s1 * (1.f / 64.f);
            float var = s2 * (1.f / 64.f) - mu * mu;
            float rs = rsqrtf(var + 1e-5f);
            h1r[t] = (xv - mu) * rs * g1 + bb1;
        }
        // projections via readlane (weights global, L1/L2 cached)
        float aq[8], ag[8], ak[8], av[8];
        #pragma unroll
        for (int t = 0; t < 8; t++) { aq[t] = 0.f; ag[t] = 0.f; ak[t] = 0.f; av[t] = 0.f; }
        for (int i = 0; i < 64; i++) {
            float wq0 = w_qg[i * 128 + c];
            float wq1 = w_qg[i * 128 + 64 + c];
            float wk0 = w_kv[i * 128 + c];
            float wk1 = w_kv[i * 128 + 64 + c];
            #pragma unroll
            for (int t = 0; t < 8; t++) {
                float hv = rl(h1r[t], i);
                aq[t] += hv * wq0; ag[t] += hv * wq1;
                ak[t] += hv * wk0; av[t] += hv * wk1;
            }
        }
        __syncthreads();  // previous iteration's phase-D reads must be done
        #pragma unroll
        for (int t = 0; t < 8; t++) {
            int n = nbase + t;
            size_t idx = (((size_t)b * NT) + n) * 64 + c;
            qb[idx]   = f2bf(aq[t] * inv_scale);
            gbuf[idx] = f2bf(ag[t]);
            vbuf[idx] = f2bf(av[t]);
            float kvl = (ak[t] + pos_enc[(size_t)n * 64 + c]) * inv_scale;
            int row = wave * 8 + t;
            kc2[row][c]      = safe_pow(kvl, pw);
            kc2[row][64 + c] = safe_pow(-kvl, pw);
            vs_[row][c] = av[t];
        }
        __syncthreads();
        // phase D: block-wide reduction accumulation (registers)
        const int kcoff = ((dj >> 5) << 6) + dh * 32 + (dj & 31);
        const int voff = dh * 32 + ds * 16;
        #pragma unroll 4
        for (int tok = 0; tok < 32; tok++) {
            float kcv = kc2[tok][kcoff];
            kmacc += (ds == 0) ? kcv : 0.f;
            const float4* vp = (const float4*)&vs_[tok][voff];
            float4 v0 = vp[0], v1 = vp[1], v2 = vp[2], v3 = vp[3];
            kvacc[0]  += kcv * v0.x; kvacc[1]  += kcv * v0.y; kvacc[2]  += kcv * v0.z; kvacc[3]  += kcv * v0.w;
            kvacc[4]  += kcv * v1.x; kvacc[5]  += kcv * v1.y; kvacc[6]  += kcv * v1.z; kvacc[7]  += kcv * v1.w;
            kvacc[8]  += kcv * v2.x; kvacc[9]  += kcv * v2.y; kvacc[10] += kcv * v2.z; kvacc[11] += kcv * v2.w;
            kvacc[12] += kcv * v3.x; kvacc[13] += kcv * v3.y; kvacc[14] += kcv * v3.z; kvacc[15] += kcv * v3.w;
        }
    }
    const float invN = 1.f / 16384.f;
    size_t kvoff = ((((size_t)b * 2 + ds) * 2 + dh) * 64 + dj) * 16;
    #pragma unroll
    for (int e = 0; e < 16; e++) atomicAdd(&kv_g[kvoff + e], kvacc[e] * invN);
    if (ds == 0) atomicAdd(&km_g[((size_t)b * 2 + dh) * 64 + dj], kmacc * invN);
}

// ---------------------------------------------------------------------------
// k2: 5x5 depthwise conv on v. wave per token, lane = channel.
// ---------------------------------------------------------------------------
__global__ __launch_bounds__(256)
void k2_dwc(const bf16* __restrict__ vbuf,
            const float* __restrict__ dwc_w, const float* __restrict__ dwc_b,
            bf16* __restrict__ vdb)
{
    const int tid = threadIdx.x;
    const int wid = blockIdx.x * 4 + (tid >> 6);
    const int c = tid & 63;
    const int d = c & 31;
    float w25[25];
    #pragma unroll
    for (int k = 0; k < 25; k++) w25[k] = dwc_w[d * 25 + k];
    const float bias = dwc_b[d];
    for (int it = 0; it < 32; ++it) {
        int t = wid * 32 + it;                 // consecutive tokens -> row reuse
        int b = t >> 14;
        int n = t & 16383;
        int y0 = n >> 7, x0 = n & 127;
        float acc = bias;
        #pragma unroll
        for (int ky = 0; ky < 5; ky++) {
            int yy = y0 + ky - 2;
            if ((unsigned)yy < 128u) {
                const bf16* rowp = vbuf + ((((size_t)b << 14) + (yy << 7)) << 6) + c;
                #pragma unroll
                for (int kx = 0; kx < 5; kx++) {
                    int xx = x0 + kx - 2;
                    if ((unsigned)xx < 128u)
                        acc += w25[ky * 5 + kx] * bf2f(rowp[(size_t)xx << 6]);
                }
            }
        }
        vdb[((((size_t)b << 14) + n) << 6) + c] = f2bf(acc);
    }
}

// ---------------------------------------------------------------------------
// k3: attention apply + gate + proj + residual + LN2 + MLP + residual
// grid (64, B), 256 threads; wave processes 8 tokens at a time.
// ---------------------------------------------------------------------------
__global__ __launch_bounds__(256)
void k3_main(const float* __restrict__ x,
             const bf16* __restrict__ qb, const bf16* __restrict__ gbuf, const bf16* __restrict__ vdb,
             const float* __restrict__ km_g, const float* __restrict__ kv_g,
             const float* __restrict__ power_p,
             const float* __restrict__ w_proj, const float* __restrict__ b_proj,
             const float* __restrict__ ln2_g, const float* __restrict__ ln2_b,
             const float* __restrict__ w_fc1, const float* __restrict__ b_fc1,
             const float* __restrict__ w_fc2, const float* __restrict__ b_fc2,
             float* __restrict__ out)
{
    const int b = blockIdx.y, chunk = blockIdx.x;
    const int tid = threadIdx.x, wave = tid >> 6, c = tid & 63;
    const int hh = c >> 5, dp = c & 31;
    const bool sim = dp < 16;
    const int e = dp & 15;

    __shared__ float kvs[2][64][16];
    __shared__ float kvo[2][64][16];
    __shared__ float kms[128];

    for (int i = tid; i < 2048; i += 256) {
        ((float*)kvs)[i] = kv_g[((size_t)b * 2 + 0) * 2048 + i];
        ((float*)kvo)[i] = kv_g[((size_t)b * 2 + 1) * 2048 + i];
    }
    if (tid < 128) kms[tid] = km_g[(size_t)b * 128 + tid];
    __syncthreads();

    const float pw = 1.f + 4.f / (1.f + __expf(-power_p[c]));
    const float bpj = b_proj[c];
    const float g2 = ln2_g[c], b2v = ln2_b[c];
    float bf1r[4];
    #pragma unroll
    for (int r = 0; r < 4; r++) bf1r[r] = b_fc1[c + 64 * r];
    const float bfc2 = b_fc2[c];
    const float km0 = kms[hh * 64 + dp];
    const float km1 = kms[hh * 64 + 32 + dp];

    const float* baseA = sim ? &kvs[hh][0][e]  : &kvo[hh][32][e];
    const float* baseB = sim ? &kvs[hh][32][e] : &kvo[hh][0][e];

    for (int iter = 0; iter < 8; ++iter) {
        const int nbase = chunk * 256 + iter * 32 + wave * 8;
        float qp[8], qn[8], xr[8], vd[8], gr[8], zsel[8];
        #pragma unroll
        for (int t = 0; t < 8; t++) {
            size_t idx = (((size_t)b * NT) + nbase + t) * 64 + c;
            float q = bf2f(qb[idx]);
            xr[t] = x[idx];
            vd[t] = bf2f(vdb[idx]);
            gr[t] = bf2f(gbuf[idx]);
            float qpv = safe_pow(q, pw);
            float qnv = safe_pow(-q, pw);
            qp[t] = qpv; qn[t] = qnv;
            float dsim = qpv * km0 + qnv * km1;
            float dopp = qnv * km0 + qpv * km1;
            #pragma unroll
            for (int m = 1; m < 32; m <<= 1) {
                dsim += __shfl_xor(dsim, m, 64);
                dopp += __shfl_xor(dopp, m, 64);
            }
            float zs = 1.f / (dsim + 1e-6f);
            float zo = 1.f / (dopp + 1e-6f);
            zsel[t] = sim ? zs : zo;
        }
        // attention apply: xacc = sum_j q_feat[j] * kv[j][e]
        float xacc[8];
        #pragma unroll
        for (int t = 0; t < 8; t++) xacc[t] = 0.f;
        for (int jm = 0; jm < 32; jm++) {
            float kA = baseA[jm * 16];
            float kB = baseB[jm * 16];
            #pragma unroll
            for (int t = 0; t < 8; t++) {
                float qp0 = rl(qp[t], jm), qp1 = rl(qp[t], 32 + jm);
                float qn0 = rl(qn[t], jm), qn1 = rl(qn[t], 32 + jm);
                float qps = hh ? qp1 : qp0;
                float qns = hh ? qn1 : qn0;
                xacc[t] += qps * kA + qns * kB;
            }
        }
        float xa[8];
        #pragma unroll
        for (int t = 0; t < 8; t++) xa[t] = (xacc[t] * zsel[t] + vd[t]) * gr[t];
        // proj (64x64)
        float ya[8];
        #pragma unroll
        for (int t = 0; t < 8; t++) ya[t] = bpj;
        for (int i = 0; i < 64; i++) {
            float w = w_proj[i * 64 + c];
            #pragma unroll
            for (int t = 0; t < 8; t++) ya[t] += rl(xa[t], i) * w;
        }
        // residual + LN2
        float xm[8], h2r[8];
        #pragma unroll
        for (int t = 0; t < 8; t++) {
            float v = xr[t] + ya[t];
            float s1 = redsum64(v);
            float s2 = redsum64(v * v);
            float mu = s1 * (1.f / 64.f);
            float var = s2 * (1.f / 64.f) - mu * mu;
            float rs = rsqrtf(var + 1e-5f);
            xm[t] = v;
            h2r[t] = (v - mu) * rs * g2 + b2v;
        }
        // fc1 (64->256) + exact gelu
        float fa[4][8];
        #pragma unroll
        for (int r = 0; r < 4; r++)
            #pragma unroll
            for (int t = 0; t < 8; t++) fa[r][t] = bf1r[r];
        for (int i = 0; i < 64; i++) {
            float w0 = w_fc1[i * 256 + c];
            float w1 = w_fc1[i * 256 + 64 + c];
            float w2 = w_fc1[i * 256 + 128 + c];
            float w3 = w_fc1[i * 256 + 192 + c];
            #pragma unroll
            for (int t = 0; t < 8; t++) {
                float hv = rl(h2r[t], i);
                fa[0][t] += hv * w0; fa[1][t] += hv * w1;
                fa[2][t] += hv * w2; fa[3][t] += hv * w3;
            }
        }
        #pragma unroll
        for (int r = 0; r < 4; r++)
            #pragma unroll
            for (int t = 0; t < 8; t++) {
                float m = fa[r][t];
                fa[r][t] = 0.5f * m * (1.f + erff(m * 0.70710678118654752f));
            }
        // fc2 (256->64)
        float oa[8];
        #pragma unroll
        for (int t = 0; t < 8; t++) oa[t] = bfc2;
        #pragma unroll
        for (int r = 0; r < 4; r++) {
            for (int l = 0; l < 64; l++) {
                float w = w_fc2[(r * 64 + l) * 64 + c];
                #pragma unroll
                for (int t = 0; t < 8; t++) oa[t] += rl(fa[r][t], l) * w;
            }
        }
        #pragma unroll
        for (int t = 0; t < 8; t++) {
            size_t idx = (((size_t)b * NT) + nbase + t) * 64 + c;
            out[idx] = xm[t] + oa[t];
        }
    }
}

// ---------------------------------------------------------------------------
extern "C" void kernel_launch(void* const* d_in, const int* in_sizes, int n_in,
                              void* d_out, int out_size, void* d_ws, size_t ws_size,
                              hipStream_t stream)
{
    const float* x       = (const float*)d_in[0];
    const float* ln1_g   = (const float*)d_in[3];
    const float* ln1_b   = (const float*)d_in[4];
    const float* w_qg    = (const float*)d_in[5];
    const float* w_kv    = (const float*)d_in[6];
    const float* pos     = (const float*)d_in[7];
    const float* scale_p = (const float*)d_in[8];
    const float* power_p = (const float*)d_in[9];
    const float* dwc_w   = (const float*)d_in[10];
    const float* dwc_b   = (const float*)d_in[11];
    const float* w_proj  = (const float*)d_in[12];
    const float* b_proj  = (const float*)d_in[13];
    const float* ln2_g   = (const float*)d_in[14];
    const float* ln2_b   = (const float*)d_in[15];
    const float* w_fc1   = (const float*)d_in[16];
    const float* b_fc1   = (const float*)d_in[17];
    const float* w_fc2   = (const float*)d_in[18];
    const float* b_fc2   = (const float*)d_in[19];
    float* out = (float*)d_out;

    // workspace layout (needs ~134.5 MB)
    size_t ntc = (size_t)NTOK * 64;
    bf16* qb   = (bf16*)d_ws;
    bf16* gbuf = qb + ntc;
    bf16* vbuf = gbuf + ntc;
    bf16* vdb  = vbuf + ntc;
    float* km_g = (float*)(vdb + ntc);              // [B][2][64]
    float* kv_g = km_g + (size_t)NB * 2 * 64;       // [B][2][2][64][16]

    hipMemsetAsync(km_g, 0, ((size_t)NB * 2 * 64 + (size_t)NB * 2 * 2 * 64 * 16) * sizeof(float), stream);

    dim3 g1(64, NB);
    k1_proj<<<g1, 256, 0, stream>>>(x, ln1_g, ln1_b, w_qg, w_kv, pos, scale_p, power_p,
                                    qb, gbuf, vbuf, km_g, kv_g);
    k2_dwc<<<2048, 256, 0, stream>>>(vbuf, dwc_w, dwc_b, vdb);
    dim3 g3(64, NB);
    k3_main<<<g3, 256, 0, stream>>>(x, qb, gbuf, vdb, km_g, kv_g, power_p,
                                    w_proj, b_proj, ln2_g, ln2_b,
                                    w_fc1, b_fc1, w_fc2, b_fc2, out);
}

// Round 2
// 519.846 us; speedup vs baseline: 2.8067x; 2.8067x over previous
//
#include <hip/hip_runtime.h>
#include <hip/hip_bf16.h>

// B=16, H=W=128, N=16384, DIM=64, HEADS=2, HD=32, MLP_H=256
#define NB 16
#define NT 16384
#define NTOK (NB * NT)

typedef __hip_bfloat16 bf16;
typedef __attribute__((ext_vector_type(8))) short short8;
typedef __attribute__((ext_vector_type(4))) float f32x4;

static __device__ __forceinline__ f32x4 MFMA(short8 a, short8 b, f32x4 c) {
    return __builtin_amdgcn_mfma_f32_16x16x32_bf16(a, b, c, 0, 0, 0);
}
static __device__ __forceinline__ short bfs(float f) {
    union { bf16 h; short s; } u; u.h = __float2bfloat16(f); return u.s;
}
static __device__ __forceinline__ float sbf(short s) {
    union { bf16 h; short s; } u; u.s = s; return __bfloat162float(u.h);
}
static __device__ __forceinline__ bf16 f2bf(float v) { return __float2bfloat16(v); }

// max(x,0)^p with 0 at 0
static __device__ __forceinline__ float safe_pow(float x, float p) {
    return (x > 0.f) ? __builtin_amdgcn_exp2f(p * __builtin_amdgcn_logf(x)) : 0.f;
}
static __device__ __forceinline__ float sigm(float y) {  // 1/(1+e^-y)
    return __builtin_amdgcn_rcpf(1.f + __builtin_amdgcn_exp2f(-1.44269504f * y));
}

// swizzled byte offset inside a [rows][32-tok] bf16 region (64B rows)
static __device__ __forceinline__ int swb(int row, int tok) {
    return row * 64 + ((tok * 2) ^ (((row >> 1) & 3) << 4));
}

// ---------------------------------------------------------------------------
// k0: pack weights into MFMA B-fragment order (bf16)
// ---------------------------------------------------------------------------
__global__ __launch_bounds__(256)
void k0_prep(const float* __restrict__ w_qg, const float* __restrict__ w_kv,
             const float* __restrict__ w_fc1, const float* __restrict__ w_fc2,
             short* __restrict__ wqk_f, short* __restrict__ wf1_f, short* __restrict__ wf2_f)
{
    int idx = blockIdx.x * 256 + threadIdx.x;
    if (idx < 16384) {
        int k = idx >> 8, col = idx & 255;
        float wv = (col < 128) ? w_qg[k * 128 + col] : w_kv[k * 128 + col - 128];
        int ct = col >> 4, ks = k >> 5, lane = (col & 15) + 16 * ((k & 31) >> 3), j = k & 7;
        wqk_f[((ct * 2 + ks) * 64 + lane) * 8 + j] = bfs(wv);
    } else if (idx < 32768) {
        int i2 = idx - 16384, k = i2 >> 8, col = i2 & 255;
        int ct = col >> 4, ks = k >> 5, lane = (col & 15) + 16 * ((k & 31) >> 3), j = k & 7;
        wf1_f[((ct * 2 + ks) * 64 + lane) * 8 + j] = bfs(w_fc1[k * 256 + col]);
    } else if (idx < 49152) {
        int i2 = idx - 32768, k = i2 >> 6, col = i2 & 63;
        int ct2 = col >> 4, ks = k >> 5, lane = (col & 15) + 16 * ((k & 31) >> 3), j = k & 7;
        wf2_f[((ct2 * 8 + ks) * 64 + lane) * 8 + j] = bfs(w_fc2[k * 64 + col]);
    }
}

// ---------------------------------------------------------------------------
// k1: LN1 + qg/kv projections (MFMA) + k features + per-(b,h) reductions (MFMA)
// grid (32, B), 256 threads; wave handles 8 tiles of 16 tokens.
// Writes per-wave reduction partials to `part` ([b][chunk][wave][4224]).
// ---------------------------------------------------------------------------
__global__ __launch_bounds__(256)
void k1_proj(const float* __restrict__ x,
             const float* __restrict__ ln1_g, const float* __restrict__ ln1_b,
             const short* __restrict__ wqk_f,
             const float* __restrict__ pos_enc,
             const float* __restrict__ scale_p, const float* __restrict__ power_p,
             bf16* __restrict__ qb, bf16* __restrict__ gbuf, bf16* __restrict__ vbuf,
             float* __restrict__ part)
{
    __shared__ __align__(16) unsigned char lds[49152];
    const int tid = threadIdx.x;
    const int b = blockIdx.y, chunk = blockIdx.x;
    const int w = tid >> 6, l = tid & 63, l15 = l & 15, g = l >> 4;
    unsigned char* kft = lds + w * 12288;   // [2h][64 fd][32 tok] bf16 swizzled
    unsigned char* vt  = kft + 8192;        // [2h][32 vc][32 tok] bf16 swizzled

    float g1v[16], b1v[16];
    #pragma unroll
    for (int j = 0; j < 8; j++) {
        g1v[j]     = ln1_g[g * 8 + j];      b1v[j]     = ln1_b[g * 8 + j];
        g1v[8 + j] = ln1_g[32 + g * 8 + j]; b1v[8 + j] = ln1_b[32 + g * 8 + j];
    }
    float isc[4], pwk[4];
    #pragma unroll
    for (int ct = 0; ct < 4; ct++) {
        int ch = l15 + 16 * ct;
        float s = scale_p[ch];
        float sp = 0.69314718f * __builtin_amdgcn_logf(1.f + __builtin_amdgcn_exp2f(1.44269504f * s));
        isc[ct] = __builtin_amdgcn_rcpf(sp);
        pwk[ct] = 1.f + 4.f * sigm(power_p[ch]);
    }

    f32x4 acc[2][2][4];
    #pragma unroll
    for (int s = 0; s < 2; s++)
        #pragma unroll
        for (int h = 0; h < 2; h++)
            #pragma unroll
            for (int mt = 0; mt < 4; mt++) { f32x4 z = {0.f,0.f,0.f,0.f}; acc[s][h][mt] = z; }
    float kmp[4] = {0.f,0.f,0.f,0.f}, kmn[4] = {0.f,0.f,0.f,0.f};

    for (int it = 0; it < 8; ++it) {
        const int tok0 = chunk * 512 + (it * 4 + w) * 16;
        const size_t rowb = (size_t)b * NT + tok0;
        const float* xrow = x + (rowb + l15) * 64;
        float4 t0 = *(const float4*)(xrow + g * 8);
        float4 t1 = *(const float4*)(xrow + g * 8 + 4);
        float4 t2 = *(const float4*)(xrow + 32 + g * 8);
        float4 t3 = *(const float4*)(xrow + 32 + g * 8 + 4);
        float xa8[8] = {t0.x,t0.y,t0.z,t0.w,t1.x,t1.y,t1.z,t1.w};
        float xb8[8] = {t2.x,t2.y,t2.z,t2.w,t3.x,t3.y,t3.z,t3.w};
        float s1 = 0.f, s2 = 0.f;
        #pragma unroll
        for (int j = 0; j < 8; j++) {
            s1 += xa8[j] + xb8[j];
            s2 += xa8[j] * xa8[j] + xb8[j] * xb8[j];
        }
        s1 += __shfl_xor(s1, 16, 64); s1 += __shfl_xor(s1, 32, 64);
        s2 += __shfl_xor(s2, 16, 64); s2 += __shfl_xor(s2, 32, 64);
        float mu = s1 * 0.015625f;
        float var = s2 * 0.015625f - mu * mu;
        float rs = rsqrtf(var + 1e-5f);
        short8 A0, A1;
        #pragma unroll
        for (int j = 0; j < 8; j++) {
            A0[j] = bfs((xa8[j] - mu) * rs * g1v[j] + b1v[j]);
            A1[j] = bfs((xb8[j] - mu) * rs * g1v[8 + j] + b1v[8 + j]);
        }
        const int tokp = (it & 1) * 16;
        #pragma unroll
        for (int ct = 0; ct < 16; ct++) {
            short8 f0 = *(const short8*)(wqk_f + (ct * 2 + 0) * 512 + l * 8);
            short8 f1 = *(const short8*)(wqk_f + (ct * 2 + 1) * 512 + l * 8);
            f32x4 c = {0.f,0.f,0.f,0.f};
            c = MFMA(A0, f0, c);
            c = MFMA(A1, f1, c);
            if (ct < 4) {            // q
                #pragma unroll
                for (int r = 0; r < 4; r++)
                    qb[(rowb + g * 4 + r) * 64 + l15 + 16 * ct] = f2bf(c[r] * isc[ct]);
            } else if (ct < 8) {     // gate
                #pragma unroll
                for (int r = 0; r < 4; r++)
                    gbuf[(rowb + g * 4 + r) * 64 + l15 + 16 * (ct - 4)] = f2bf(c[r]);
            } else if (ct < 12) {    // k -> features
                const int ctk = ct - 8, kchan = l15 + 16 * ctk;
                const int hh = kchan >> 5, d = kchan & 31;
                #pragma unroll
                for (int r = 0; r < 4; r++) {
                    int n = tok0 + g * 4 + r;
                    float kvl = (c[r] + pos_enc[(size_t)n * 64 + kchan]) * isc[ctk];
                    float kp = safe_pow(kvl, pwk[ctk]);
                    float kn = safe_pow(-kvl, pwk[ctk]);
                    kmp[ctk] += kp; kmn[ctk] += kn;
                    int tk = tokp + g * 4 + r;
                    *(short*)(kft + swb(hh * 64 + d, tk))      = bfs(kp);
                    *(short*)(kft + swb(hh * 64 + 32 + d, tk)) = bfs(kn);
                }
            } else {                 // v
                const int ctv = ct - 12, vchan = l15 + 16 * ctv;
                const int hh = vchan >> 5, vc = vchan & 31;
                #pragma unroll
                for (int r = 0; r < 4; r++) {
                    int tk = tokp + g * 4 + r;
                    vbuf[(rowb + g * 4 + r) * 64 + vchan] = f2bf(c[r]);
                    *(short*)(vt + swb(hh * 32 + vc, tk)) = bfs(c[r]);
                }
            }
        }
        if (it & 1) {  // reduction over 32 staged tokens
            #pragma unroll
            for (int h = 0; h < 2; h++) {
                int rv0 = h * 32 + l15, rv1 = h * 32 + 16 + l15;
                short8 Bv0 = *(const short8*)(vt + rv0 * 64 + ((g * 16) ^ (((rv0 >> 1) & 3) << 4)));
                short8 Bv1 = *(const short8*)(vt + rv1 * 64 + ((g * 16) ^ (((rv1 >> 1) & 3) << 4)));
                #pragma unroll
                for (int mt = 0; mt < 4; mt++) {
                    int rk = h * 64 + mt * 16 + l15;
                    short8 Ak = *(const short8*)(kft + rk * 64 + ((g * 16) ^ (((rk >> 1) & 3) << 4)));
                    acc[0][h][mt] = MFMA(Ak, Bv0, acc[0][h][mt]);
                    acc[1][h][mt] = MFMA(Ak, Bv1, acc[1][h][mt]);
                }
            }
        }
    }
    // flush per-wave partials
    float* pw_ = part + (((size_t)(b * 32 + chunk)) * 4 + w) * 4224;
    #pragma unroll
    for (int s = 0; s < 2; s++)
        #pragma unroll
        for (int h = 0; h < 2; h++)
            #pragma unroll
            for (int mt = 0; mt < 4; mt++)
                #pragma unroll
                for (int r = 0; r < 4; r++)
                    pw_[((s * 2 + h) * 64 + mt * 16 + g * 4 + r) * 16 + l15] = acc[s][h][mt][r];
    #pragma unroll
    for (int ct = 0; ct < 4; ct++) {
        kmp[ct] += __shfl_xor(kmp[ct], 16, 64); kmp[ct] += __shfl_xor(kmp[ct], 32, 64);
        kmn[ct] += __shfl_xor(kmn[ct], 16, 64); kmn[ct] += __shfl_xor(kmn[ct], 32, 64);
    }
    if (g == 0) {
        #pragma unroll
        for (int ct = 0; ct < 4; ct++) {
            int kchan = l15 + 16 * ct, hh = kchan >> 5, d = kchan & 31;
            pw_[4096 + hh * 64 + d]      = kmp[ct];
            pw_[4096 + hh * 64 + 32 + d] = kmn[ct];
        }
    }
}

// ---------------------------------------------------------------------------
// k1b: reduce 128 partials per b -> km_g, kv_g (scaled by 1/N)
// ---------------------------------------------------------------------------
__global__ __launch_bounds__(256)
void k1b_reduce(const float* __restrict__ part, float* __restrict__ km_g, float* __restrict__ kv_g)
{
    int b = blockIdx.y;
    int i = blockIdx.x * 256 + threadIdx.x;
    if (i >= 4224) return;
    const float* p = part + (size_t)b * 128 * 4224 + i;
    float s = 0.f;
    for (int c = 0; c < 128; c++) s += p[(size_t)c * 4224];
    s *= (1.f / 16384.f);
    if (i < 4096) kv_g[(size_t)b * 4096 + i] = s;
    else          km_g[(size_t)b * 128 + (i - 4096)] = s;
}

// ---------------------------------------------------------------------------
// k2: 5x5 depthwise conv on v. wave per token group, lane = channel.
// ---------------------------------------------------------------------------
__global__ __launch_bounds__(256)
void k2_dwc(const bf16* __restrict__ vbuf,
            const float* __restrict__ dwc_w, const float* __restrict__ dwc_b,
            bf16* __restrict__ vdb)
{
    const int tid = threadIdx.x;
    const int wid = blockIdx.x * 4 + (tid >> 6);
    const int c = tid & 63;
    const int d = c & 31;
    float w25[25];
    #pragma unroll
    for (int k = 0; k < 25; k++) w25[k] = dwc_w[d * 25 + k];
    const float bias = dwc_b[d];
    for (int it = 0; it < 32; ++it) {
        int t = wid * 32 + it;
        int b = t >> 14;
        int n = t & 16383;
        int y0 = n >> 7, x0 = n & 127;
        float acc = bias;
        #pragma unroll
        for (int ky = 0; ky < 5; ky++) {
            int yy = y0 + ky - 2;
            if ((unsigned)yy < 128u) {
                const bf16* rowp = vbuf + ((((size_t)b << 14) + (yy << 7)) << 6) + c;
                #pragma unroll
                for (int kx = 0; kx < 5; kx++) {
                    int xx = x0 + kx - 2;
                    if ((unsigned)xx < 128u)
                        acc += w25[ky * 5 + kx] * __bfloat162float(rowp[(size_t)xx << 6]);
                }
            }
        }
        vdb[((((size_t)b << 14) + n) << 6) + c] = f2bf(acc);
    }
}

// ---------------------------------------------------------------------------
// k3: attn apply + gate + proj + residual + LN2 + MLP + residual (MFMA)
// grid (64, B), 256 threads; wave handles 4 tiles of 16 tokens.
// ---------------------------------------------------------------------------
__global__ __launch_bounds__(256)
void k3_main(const float* __restrict__ x,
             const bf16* __restrict__ qb, const bf16* __restrict__ gbuf, const bf16* __restrict__ vdb,
             const float* __restrict__ km_g, const float* __restrict__ kv_g,
             const float* __restrict__ power_p,
             const float* __restrict__ w_proj, const float* __restrict__ b_proj,
             const float* __restrict__ ln2_g, const float* __restrict__ ln2_b,
             const short* __restrict__ wf1_f, const short* __restrict__ wf2_f,
             const float* __restrict__ b_fc1, const float* __restrict__ b_fc2,
             float* __restrict__ out)
{
    __shared__ __align__(16) unsigned char lds[8192];
    const int tid = threadIdx.x, b = blockIdx.y, chunk = blockIdx.x;
    const int w = tid >> 6, l = tid & 63, l15 = l & 15, g = l >> 4;
    unsigned char* tb = lds + w * 2048;   // per-wave [16 tok][64 chan] bf16, XOR-swizzled

    // register-resident constants
    short8 Wp[4][2];
    #pragma unroll
    for (int ct = 0; ct < 4; ct++)
        #pragma unroll
        for (int ks = 0; ks < 2; ks++)
            #pragma unroll
            for (int j = 0; j < 8; j++)
                Wp[ct][ks][j] = bfs(w_proj[(ks * 32 + g * 8 + j) * 64 + ct * 16 + l15]);
    short8 Bkv[2][2][2];  // [s][h][ks]
    #pragma unroll
    for (int s = 0; s < 2; s++)
        #pragma unroll
        for (int h = 0; h < 2; h++)
            #pragma unroll
            for (int ks = 0; ks < 2; ks++)
                #pragma unroll
                for (int j = 0; j < 8; j++)
                    Bkv[s][h][ks][j] = bfs(kv_g[(size_t)b * 4096 +
                        ((size_t)(s * 2 + h) * 64 + ks * 32 + g * 8 + j) * 16 + l15]);
    float kmP[2][8], kmN[2][8], pw3[2][8];
    #pragma unroll
    for (int h = 0; h < 2; h++)
        #pragma unroll
        for (int j = 0; j < 8; j++) {
            int d = g * 8 + j;
            kmP[h][j] = km_g[b * 128 + h * 64 + d];
            kmN[h][j] = km_g[b * 128 + h * 64 + 32 + d];
            pw3[h][j] = 1.f + 4.f * sigm(power_p[h * 32 + d]);
        }
    float bpj[4], g2[4], b2[4], bfc2v[4];
    #pragma unroll
    for (int ct = 0; ct < 4; ct++) {
        int ch = l15 + 16 * ct;
        bpj[ct] = b_proj[ch]; g2[ct] = ln2_g[ch]; b2[ct] = ln2_b[ch]; bfc2v[ct] = b_fc2[ch];
    }
    float bf1v[16];
    #pragma unroll
    for (int ct = 0; ct < 16; ct++) bf1v[ct] = b_fc1[ct * 16 + l15];

    for (int it = 0; it < 4; ++it) {
        const int tok0 = chunk * 256 + (it * 4 + w) * 16;
        const size_t rowb = (size_t)b * NT + tok0;

        // ---- phase A: q features + z
        short8 Fqp[2], Fqn[2];
        float zs[2], zo[2];
        #pragma unroll
        for (int h = 0; h < 2; h++) {
            short8 q8 = *(const short8*)((const short*)qb + (rowb + l15) * 64 + h * 32 + g * 8);
            float ds_ = 0.f, do_ = 0.f;
            #pragma unroll
            for (int j = 0; j < 8; j++) {
                float q = sbf(q8[j]);
                float qp = safe_pow(q, pw3[h][j]);
                float qn = safe_pow(-q, pw3[h][j]);
                ds_ += qp * kmP[h][j] + qn * kmN[h][j];
                do_ += qn * kmP[h][j] + qp * kmN[h][j];
                Fqp[h][j] = bfs(qp); Fqn[h][j] = bfs(qn);
            }
            ds_ += __shfl_xor(ds_, 16, 64); ds_ += __shfl_xor(ds_, 32, 64);
            do_ += __shfl_xor(do_, 16, 64); do_ += __shfl_xor(do_, 32, 64);
            zs[h] = __builtin_amdgcn_rcpf(ds_ + 1e-6f);
            zo[h] = __builtin_amdgcn_rcpf(do_ + 1e-6f);
        }

        // ---- phase B: attention MFMA
        f32x4 at[4];
        #pragma unroll
        for (int hs = 0; hs < 4; hs++) { f32x4 z4 = {0.f,0.f,0.f,0.f}; at[hs] = z4; }
        #pragma unroll
        for (int h = 0; h < 2; h++) {
            at[h*2+0] = MFMA(Fqp[h], Bkv[0][h][0], at[h*2+0]);
            at[h*2+0] = MFMA(Fqn[h], Bkv[0][h][1], at[h*2+0]);
            at[h*2+1] = MFMA(Fqn[h], Bkv[1][h][0], at[h*2+1]);
            at[h*2+1] = MFMA(Fqp[h], Bkv[1][h][1], at[h*2+1]);
        }

        // ---- phase C: z-scale, transpose, + dwc, * gate
        #pragma unroll
        for (int hs = 0; hs < 4; hs++) {
            int h = hs >> 1, s = hs & 1;
            float zv = s ? zo[h] : zs[h];
            int cb = h * 32 + s * 16;
            #pragma unroll
            for (int r = 0; r < 4; r++) {
                float zz = __shfl(zv, g * 4 + r, 64);
                int tok = g * 4 + r;
                *(short*)(tb + tok * 128 + (((cb + l15) * 2) ^ ((tok & 7) << 4))) = bfs(at[hs][r] * zz);
            }
        }
        short8 Ap[2];
        #pragma unroll
        for (int ks = 0; ks < 2; ks++) {
            short8 t8 = *(short8*)(tb + l15 * 128 + ((ks * 64 + g * 16) ^ ((l15 & 7) << 4)));
            const size_t goff = (rowb + l15) * 64 + ks * 32 + g * 8;
            short8 vd8 = *(const short8*)((const short*)vdb + goff);
            short8 g8  = *(const short8*)((const short*)gbuf + goff);
            #pragma unroll
            for (int j = 0; j < 8; j++)
                Ap[ks][j] = bfs((sbf(t8[j]) + sbf(vd8[j])) * sbf(g8[j]));
        }

        // ---- phase D: proj
        f32x4 pc[4];
        #pragma unroll
        for (int ct = 0; ct < 4; ct++) {
            f32x4 z4 = {0.f,0.f,0.f,0.f};
            z4 = MFMA(Ap[0], Wp[ct][0], z4);
            pc[ct] = MFMA(Ap[1], Wp[ct][1], z4);
        }

        // ---- phase E: residual + LN2
        float xm[4][4], h2v[4][4];
        #pragma unroll
        for (int ct = 0; ct < 4; ct++)
            #pragma unroll
            for (int r = 0; r < 4; r++)
                xm[ct][r] = x[(rowb + g * 4 + r) * 64 + l15 + 16 * ct] + pc[ct][r] + bpj[ct];
        #pragma unroll
        for (int r = 0; r < 4; r++) {
            float s1 = xm[0][r] + xm[1][r] + xm[2][r] + xm[3][r];
            float s2 = xm[0][r]*xm[0][r] + xm[1][r]*xm[1][r] + xm[2][r]*xm[2][r] + xm[3][r]*xm[3][r];
            #pragma unroll
            for (int m = 1; m < 16; m <<= 1) { s1 += __shfl_xor(s1, m, 64); s2 += __shfl_xor(s2, m, 64); }
            float mu = s1 * 0.015625f;
            float var = s2 * 0.015625f - mu * mu;
            float rs = rsqrtf(var + 1e-5f);
            #pragma unroll
            for (int ct = 0; ct < 4; ct++)
                h2v[ct][r] = (xm[ct][r] - mu) * rs * g2[ct] + b2[ct];
        }

        // ---- phase F: h2 transpose
        #pragma unroll
        for (int ct = 0; ct < 4; ct++)
            #pragma unroll
            for (int r = 0; r < 4; r++) {
                int tok = g * 4 + r;
                *(short*)(tb + tok * 128 + (((ct * 16 + l15) * 2) ^ ((tok & 7) << 4))) = bfs(h2v[ct][r]);
            }
        short8 Ah[2];
        #pragma unroll
        for (int ks = 0; ks < 2; ks++)
            Ah[ks] = *(short8*)(tb + l15 * 128 + ((ks * 64 + g * 16) ^ ((l15 & 7) << 4)));

        // ---- phase G: fc1 + gelu + fc2 (chunked over 4 groups of 64 fc1-cols)
        f32x4 a2[4];
        #pragma unroll
        for (int ct = 0; ct < 4; ct++) { f32x4 z4 = {0.f,0.f,0.f,0.f}; a2[ct] = z4; }
        #pragma unroll
        for (int g4 = 0; g4 < 4; g4++) {
            f32x4 fc[4];
            #pragma unroll
            for (int ctl = 0; ctl < 4; ctl++) {
                int ct = g4 * 4 + ctl;
                short8 f0 = *(const short8*)(wf1_f + (ct * 2 + 0) * 512 + l * 8);
                short8 f1 = *(const short8*)(wf1_f + (ct * 2 + 1) * 512 + l * 8);
                f32x4 z4 = {0.f,0.f,0.f,0.f};
                z4 = MFMA(Ah[0], f0, z4);
                fc[ctl] = MFMA(Ah[1], f1, z4);
            }
            #pragma unroll
            for (int ctl = 0; ctl < 4; ctl++)
                #pragma unroll
                for (int r = 0; r < 4; r++) {
                    float mv = fc[ctl][r] + bf1v[g4 * 4 + ctl];
                    float gl = mv * __builtin_amdgcn_rcpf(1.f +
                        __builtin_amdgcn_exp2f(mv * (-2.30220825f - 0.10294385f * mv * mv)));
                    int tok = g * 4 + r;
                    *(short*)(tb + tok * 128 + (((ctl * 16 + l15) * 2) ^ ((tok & 7) << 4))) = bfs(gl);
                }
            #pragma unroll
            for (int ksl = 0; ksl < 2; ksl++) {
                short8 Ag = *(short8*)(tb + l15 * 128 + ((ksl * 64 + g * 16) ^ ((l15 & 7) << 4)));
                int ks = g4 * 2 + ksl;
                #pragma unroll
                for (int ct2 = 0; ct2 < 4; ct2++) {
                    short8 wv = *(const short8*)(wf2_f + (ct2 * 8 + ks) * 512 + l * 8);
                    a2[ct2] = MFMA(Ag, wv, a2[ct2]);
                }
            }
        }

        // ---- phase H: output
        #pragma unroll
        for (int ct = 0; ct < 4; ct++)
            #pragma unroll
            for (int r = 0; r < 4; r++)
                out[(rowb + g * 4 + r) * 64 + l15 + 16 * ct] = xm[ct][r] + a2[ct][r] + bfc2v[ct];
    }
}

// ---------------------------------------------------------------------------
extern "C" void kernel_launch(void* const* d_in, const int* in_sizes, int n_in,
                              void* d_out, int out_size, void* d_ws, size_t ws_size,
                              hipStream_t stream)
{
    const float* x       = (const float*)d_in[0];
    const float* ln1_g   = (const float*)d_in[3];
    const float* ln1_b   = (const float*)d_in[4];
    const float* w_qg    = (const float*)d_in[5];
    const float* w_kv    = (const float*)d_in[6];
    const float* pos     = (const float*)d_in[7];
    const float* scale_p = (const float*)d_in[8];
    const float* power_p = (const float*)d_in[9];
    const float* dwc_w   = (const float*)d_in[10];
    const float* dwc_b   = (const float*)d_in[11];
    const float* w_proj  = (const float*)d_in[12];
    const float* b_proj  = (const float*)d_in[13];
    const float* ln2_g   = (const float*)d_in[14];
    const float* ln2_b   = (const float*)d_in[15];
    const float* w_fc1   = (const float*)d_in[16];
    const float* b_fc1   = (const float*)d_in[17];
    const float* w_fc2   = (const float*)d_in[18];
    const float* b_fc2   = (const float*)d_in[19];
    float* out = (float*)d_out;

    // workspace layout
    size_t ntc = (size_t)NTOK * 64;
    bf16* qb   = (bf16*)d_ws;
    bf16* gbuf = qb + ntc;
    bf16* vbuf = gbuf + ntc;
    bf16* vdb  = vbuf + ntc;
    float* km_g = (float*)(vdb + ntc);               // [B][128]
    float* kv_g = km_g + (size_t)NB * 128;           // [B][4096]
    short* wqk_f = (short*)(kv_g + (size_t)NB * 4096);
    short* wf1_f = wqk_f + 16384;
    short* wf2_f = wf1_f + 16384;

    // reduction partials live in d_out (scratch before k3 overwrites it)
    float* part = (float*)d_out;  // [B][32][4][4224] = 34.6 MB < 64 MB

    k0_prep<<<dim3(192), 256, 0, stream>>>(w_qg, w_kv, w_fc1, w_fc2, wqk_f, wf1_f, wf2_f);
    k1_proj<<<dim3(32, NB), 256, 0, stream>>>(x, ln1_g, ln1_b, wqk_f, pos, scale_p, power_p,
                                              qb, gbuf, vbuf, part);
    k1b_reduce<<<dim3(17, NB), 256, 0, stream>>>(part, km_g, kv_g);
    k2_dwc<<<2048, 256, 0, stream>>>(vbuf, dwc_w, dwc_b, vdb);
    k3_main<<<dim3(64, NB), 256, 0, stream>>>(x, qb, gbuf, vdb, km_g, kv_g, power_p,
                                              w_proj, b_proj, ln2_g, ln2_b,
                                              wf1_f, wf2_f, b_fc1, b_fc2, out);
}

// Round 3
// 327.165 us; speedup vs baseline: 4.4596x; 1.5889x over previous
//
#include <hip/hip_runtime.h>
#include <hip/hip_bf16.h>

// B=16, H=W=128, N=16384, DIM=64, HEADS=2, HD=32, MLP_H=256
#define NB 16
#define NT 16384
#define NTOK (NB * NT)

typedef __hip_bfloat16 bf16;
typedef __attribute__((ext_vector_type(8))) short short8;
typedef __attribute__((ext_vector_type(4))) float f32x4;

static __device__ __forceinline__ f32x4 MFMA(short8 a, short8 b, f32x4 c) {
    return __builtin_amdgcn_mfma_f32_16x16x32_bf16(a, b, c, 0, 0, 0);
}
static __device__ __forceinline__ short bfs(float f) {
    union { bf16 h; short s; } u; u.h = __float2bfloat16(f); return u.s;
}
static __device__ __forceinline__ float sbf(short s) {
    union { bf16 h; short s; } u; u.s = s; return __bfloat162float(u.h);
}
static __device__ __forceinline__ bf16 f2bf(float v) { return __float2bfloat16(v); }
static __device__ __forceinline__ float us2f(unsigned short u) {
    union { unsigned int i; float f; } x; x.i = ((unsigned int)u) << 16; return x.f;
}

// max(x,0)^p with 0 at 0
static __device__ __forceinline__ float safe_pow(float x, float p) {
    return (x > 0.f) ? __builtin_amdgcn_exp2f(p * __builtin_amdgcn_logf(x)) : 0.f;
}
static __device__ __forceinline__ float sigm(float y) {  // 1/(1+e^-y)
    return __builtin_amdgcn_rcpf(1.f + __builtin_amdgcn_exp2f(-1.44269504f * y));
}

// swizzled byte offset inside a [rows][32-tok] bf16 region (64B rows)
static __device__ __forceinline__ int swb(int row, int tok) {
    return row * 64 + ((tok * 2) ^ (((row >> 1) & 3) << 4));
}

// ---------------------------------------------------------------------------
// k0: pack weights into MFMA B-fragment order (bf16)
// ---------------------------------------------------------------------------
__global__ __launch_bounds__(256)
void k0_prep(const float* __restrict__ w_qg, const float* __restrict__ w_kv,
             const float* __restrict__ w_fc1, const float* __restrict__ w_fc2,
             short* __restrict__ wqk_f, short* __restrict__ wf1_f, short* __restrict__ wf2_f)
{
    int idx = blockIdx.x * 256 + threadIdx.x;
    if (idx < 16384) {
        int k = idx >> 8, col = idx & 255;
        float wv = (col < 128) ? w_qg[k * 128 + col] : w_kv[k * 128 + col - 128];
        int ct = col >> 4, ks = k >> 5, lane = (col & 15) + 16 * ((k & 31) >> 3), j = k & 7;
        wqk_f[((ct * 2 + ks) * 64 + lane) * 8 + j] = bfs(wv);
    } else if (idx < 32768) {
        int i2 = idx - 16384, k = i2 >> 8, col = i2 & 255;
        int ct = col >> 4, ks = k >> 5, lane = (col & 15) + 16 * ((k & 31) >> 3), j = k & 7;
        wf1_f[((ct * 2 + ks) * 64 + lane) * 8 + j] = bfs(w_fc1[k * 256 + col]);
    } else if (idx < 49152) {
        int i2 = idx - 32768, k = i2 >> 6, col = i2 & 63;
        int ct2 = col >> 4, ks = k >> 5, lane = (col & 15) + 16 * ((k & 31) >> 3), j = k & 7;
        wf2_f[((ct2 * 8 + ks) * 64 + lane) * 8 + j] = bfs(w_fc2[k * 64 + col]);
    }
}

// ---------------------------------------------------------------------------
// k1: LN1 + qg/kv projections (MFMA) + k features + per-(b,h) reductions (MFMA)
// grid (32, B), 256 threads; wave handles 8 tiles of 16 tokens.
// Writes per-wave reduction partials to `part` ([b][chunk][wave][4224]).
// ---------------------------------------------------------------------------
__global__ __launch_bounds__(256)
void k1_proj(const float* __restrict__ x,
             const float* __restrict__ ln1_g, const float* __restrict__ ln1_b,
             const short* __restrict__ wqk_f,
             const float* __restrict__ pos_enc,
             const float* __restrict__ scale_p, const float* __restrict__ power_p,
             bf16* __restrict__ qb, bf16* __restrict__ gbuf, bf16* __restrict__ vbuf,
             float* __restrict__ part)
{
    __shared__ __align__(16) unsigned char lds[49152];
    const int tid = threadIdx.x;
    const int b = blockIdx.y, chunk = blockIdx.x;
    const int w = tid >> 6, l = tid & 63, l15 = l & 15, g = l >> 4;
    unsigned char* kft = lds + w * 12288;   // [2h][64 fd][32 tok] bf16 swizzled
    unsigned char* vt  = kft + 8192;        // [2h][32 vc][32 tok] bf16 swizzled

    float g1v[16], b1v[16];
    #pragma unroll
    for (int j = 0; j < 8; j++) {
        g1v[j]     = ln1_g[g * 8 + j];      b1v[j]     = ln1_b[g * 8 + j];
        g1v[8 + j] = ln1_g[32 + g * 8 + j]; b1v[8 + j] = ln1_b[32 + g * 8 + j];
    }
    float isc[4], pwk[4];
    #pragma unroll
    for (int ct = 0; ct < 4; ct++) {
        int ch = l15 + 16 * ct;
        float s = scale_p[ch];
        float sp = 0.69314718f * __builtin_amdgcn_logf(1.f + __builtin_amdgcn_exp2f(1.44269504f * s));
        isc[ct] = __builtin_amdgcn_rcpf(sp);
        pwk[ct] = 1.f + 4.f * sigm(power_p[ch]);
    }

    f32x4 acc[2][2][4];
    #pragma unroll
    for (int s = 0; s < 2; s++)
        #pragma unroll
        for (int h = 0; h < 2; h++)
            #pragma unroll
            for (int mt = 0; mt < 4; mt++) { f32x4 z = {0.f,0.f,0.f,0.f}; acc[s][h][mt] = z; }
    float kmp[4] = {0.f,0.f,0.f,0.f}, kmn[4] = {0.f,0.f,0.f,0.f};

    for (int it = 0; it < 8; ++it) {
        const int tok0 = chunk * 512 + (it * 4 + w) * 16;
        const size_t rowb = (size_t)b * NT + tok0;
        const float* xrow = x + (rowb + l15) * 64;
        float4 t0 = *(const float4*)(xrow + g * 8);
        float4 t1 = *(const float4*)(xrow + g * 8 + 4);
        float4 t2 = *(const float4*)(xrow + 32 + g * 8);
        float4 t3 = *(const float4*)(xrow + 32 + g * 8 + 4);
        float xa8[8] = {t0.x,t0.y,t0.z,t0.w,t1.x,t1.y,t1.z,t1.w};
        float xb8[8] = {t2.x,t2.y,t2.z,t2.w,t3.x,t3.y,t3.z,t3.w};
        float s1 = 0.f, s2 = 0.f;
        #pragma unroll
        for (int j = 0; j < 8; j++) {
            s1 += xa8[j] + xb8[j];
            s2 += xa8[j] * xa8[j] + xb8[j] * xb8[j];
        }
        s1 += __shfl_xor(s1, 16, 64); s1 += __shfl_xor(s1, 32, 64);
        s2 += __shfl_xor(s2, 16, 64); s2 += __shfl_xor(s2, 32, 64);
        float mu = s1 * 0.015625f;
        float var = s2 * 0.015625f - mu * mu;
        float rs = rsqrtf(var + 1e-5f);
        short8 A0, A1;
        #pragma unroll
        for (int j = 0; j < 8; j++) {
            A0[j] = bfs((xa8[j] - mu) * rs * g1v[j] + b1v[j]);
            A1[j] = bfs((xb8[j] - mu) * rs * g1v[8 + j] + b1v[8 + j]);
        }
        const int tokp = (it & 1) * 16;
        #pragma unroll
        for (int ct = 0; ct < 16; ct++) {
            short8 f0 = *(const short8*)(wqk_f + (ct * 2 + 0) * 512 + l * 8);
            short8 f1 = *(const short8*)(wqk_f + (ct * 2 + 1) * 512 + l * 8);
            f32x4 c = {0.f,0.f,0.f,0.f};
            c = MFMA(A0, f0, c);
            c = MFMA(A1, f1, c);
            if (ct < 4) {            // q
                #pragma unroll
                for (int r = 0; r < 4; r++)
                    qb[(rowb + g * 4 + r) * 64 + l15 + 16 * ct] = f2bf(c[r] * isc[ct]);
            } else if (ct < 8) {     // gate
                #pragma unroll
                for (int r = 0; r < 4; r++)
                    gbuf[(rowb + g * 4 + r) * 64 + l15 + 16 * (ct - 4)] = f2bf(c[r]);
            } else if (ct < 12) {    // k -> features
                const int ctk = ct - 8, kchan = l15 + 16 * ctk;
                const int hh = kchan >> 5, d = kchan & 31;
                #pragma unroll
                for (int r = 0; r < 4; r++) {
                    int n = tok0 + g * 4 + r;
                    float kvl = (c[r] + pos_enc[(size_t)n * 64 + kchan]) * isc[ctk];
                    float kp = safe_pow(kvl, pwk[ctk]);
                    float kn = safe_pow(-kvl, pwk[ctk]);
                    kmp[ctk] += kp; kmn[ctk] += kn;
                    int tk = tokp + g * 4 + r;
                    *(short*)(kft + swb(hh * 64 + d, tk))      = bfs(kp);
                    *(short*)(kft + swb(hh * 64 + 32 + d, tk)) = bfs(kn);
                }
            } else {                 // v
                const int ctv = ct - 12, vchan = l15 + 16 * ctv;
                const int hh = vchan >> 5, vc = vchan & 31;
                #pragma unroll
                for (int r = 0; r < 4; r++) {
                    int tk = tokp + g * 4 + r;
                    vbuf[(rowb + g * 4 + r) * 64 + vchan] = f2bf(c[r]);
                    *(short*)(vt + swb(hh * 32 + vc, tk)) = bfs(c[r]);
                }
            }
        }
        if (it & 1) {  // reduction over 32 staged tokens
            #pragma unroll
            for (int h = 0; h < 2; h++) {
                int rv0 = h * 32 + l15, rv1 = h * 32 + 16 + l15;
                short8 Bv0 = *(const short8*)(vt + rv0 * 64 + ((g * 16) ^ (((rv0 >> 1) & 3) << 4)));
                short8 Bv1 = *(const short8*)(vt + rv1 * 64 + ((g * 16) ^ (((rv1 >> 1) & 3) << 4)));
                #pragma unroll
                for (int mt = 0; mt < 4; mt++) {
                    int rk = h * 64 + mt * 16 + l15;
                    short8 Ak = *(const short8*)(kft + rk * 64 + ((g * 16) ^ (((rk >> 1) & 3) << 4)));
                    acc[0][h][mt] = MFMA(Ak, Bv0, acc[0][h][mt]);
                    acc[1][h][mt] = MFMA(Ak, Bv1, acc[1][h][mt]);
                }
            }
        }
    }
    // flush per-wave partials
    float* pw_ = part + (((size_t)(b * 32 + chunk)) * 4 + w) * 4224;
    #pragma unroll
    for (int s = 0; s < 2; s++)
        #pragma unroll
        for (int h = 0; h < 2; h++)
            #pragma unroll
            for (int mt = 0; mt < 4; mt++)
                #pragma unroll
                for (int r = 0; r < 4; r++)
                    pw_[((s * 2 + h) * 64 + mt * 16 + g * 4 + r) * 16 + l15] = acc[s][h][mt][r];
    #pragma unroll
    for (int ct = 0; ct < 4; ct++) {
        kmp[ct] += __shfl_xor(kmp[ct], 16, 64); kmp[ct] += __shfl_xor(kmp[ct], 32, 64);
        kmn[ct] += __shfl_xor(kmn[ct], 16, 64); kmn[ct] += __shfl_xor(kmn[ct], 32, 64);
    }
    if (g == 0) {
        #pragma unroll
        for (int ct = 0; ct < 4; ct++) {
            int kchan = l15 + 16 * ct, hh = kchan >> 5, d = kchan & 31;
            pw_[4096 + hh * 64 + d]      = kmp[ct];
            pw_[4096 + hh * 64 + 32 + d] = kmn[ct];
        }
    }
}

// ---------------------------------------------------------------------------
// k1b: reduce 128 partials per b -> km_g, kv_g (scaled by 1/N)
// ---------------------------------------------------------------------------
__global__ __launch_bounds__(256)
void k1b_reduce(const float* __restrict__ part, float* __restrict__ km_g, float* __restrict__ kv_g)
{
    int b = blockIdx.y;
    int i = blockIdx.x * 256 + threadIdx.x;
    if (i >= 4224) return;
    const float* p = part + (size_t)b * 128 * 4224 + i;
    float s = 0.f;
    for (int c = 0; c < 128; c++) s += p[(size_t)c * 4224];
    s *= (1.f / 16384.f);
    if (i < 4096) kv_g[(size_t)b * 4096 + i] = s;
    else          km_g[(size_t)b * 128 + (i - 4096)] = s;
}

// ---------------------------------------------------------------------------
// k2: 5x5 depthwise conv. Block = 32x8 spatial tile of one image.
// LDS-staged halo tile (36x12 x 64ch bf16), per-lane sliding 5x5 window.
// grid (64 tiles, B), 256 threads. Lane = channel; wave owns 2 y-rows.
// ---------------------------------------------------------------------------
__global__ __launch_bounds__(256)
void k2_dwc(const bf16* __restrict__ vbuf,
            const float* __restrict__ dwc_w, const float* __restrict__ dwc_b,
            bf16* __restrict__ vdb)
{
    __shared__ __align__(16) unsigned short tile[12][36][64];   // 55296 B
    const int tid = threadIdx.x;
    const int b = blockIdx.y;
    const int ty = blockIdx.x >> 2, tx = blockIdx.x & 3;
    const int y0 = ty * 8, x0 = tx * 32;

    // ---- stage halo tile: 12 rows x 36 tokens x 64 ch, 8B per thread-chunk
    #pragma unroll
    for (int i = 0; i < 27; ++i) {
        int cid = i * 256 + tid;          // 0..6911
        int yy = cid / 576;               // 576 = 36*16 chunks per row
        int rem = cid - yy * 576;
        int xx = rem >> 4;
        int c4 = rem & 15;
        int Y = y0 - 2 + yy, X = x0 - 2 + xx;
        uint2 val = make_uint2(0u, 0u);
        if ((unsigned)Y < 128u && (unsigned)X < 128u)
            val = *(const uint2*)(vbuf + (((size_t)b * NT + Y * 128 + X) * 64 + c4 * 4));
        *(uint2*)(&tile[yy][xx][c4 * 4]) = val;
    }
    __syncthreads();

    const int w = tid >> 6, c = tid & 63, d = c & 31;
    float wt[25];
    #pragma unroll
    for (int k = 0; k < 25; k++) wt[k] = dwc_w[d * 25 + k];
    const float bias = dwc_b[d];

    #pragma unroll
    for (int yl2 = 0; yl2 < 2; ++yl2) {
        const int yl = w * 2 + yl2;
        float cw[5][5];  // cw[ky][xx%5]
        #pragma unroll
        for (int xx = 0; xx < 4; ++xx)
            #pragma unroll
            for (int ky = 0; ky < 5; ++ky)
                cw[ky][xx] = us2f(tile[yl + ky][xx][c]);
        #pragma unroll
        for (int xl = 0; xl < 32; ++xl) {
            const int jn = (xl + 4) % 5;
            #pragma unroll
            for (int ky = 0; ky < 5; ++ky)
                cw[ky][jn] = us2f(tile[yl + ky][xl + 4][c]);
            float acc = bias;
            #pragma unroll
            for (int ky = 0; ky < 5; ++ky)
                #pragma unroll
                for (int kx = 0; kx < 5; ++kx)
                    acc += wt[ky * 5 + kx] * cw[ky][(xl + kx) % 5];
            const int Y = y0 + yl, X = x0 + xl;
            vdb[((size_t)b * NT + Y * 128 + X) * 64 + c] = f2bf(acc);
        }
    }
}

// ---------------------------------------------------------------------------
// k3: attn apply + gate + proj + residual + LN2 + MLP + residual (MFMA)
// grid (64, B), 256 threads; wave handles 4 tiles of 16 tokens.
// ---------------------------------------------------------------------------
__global__ __launch_bounds__(256)
void k3_main(const float* __restrict__ x,
             const bf16* __restrict__ qb, const bf16* __restrict__ gbuf, const bf16* __restrict__ vdb,
             const float* __restrict__ km_g, const float* __restrict__ kv_g,
             const float* __restrict__ power_p,
             const float* __restrict__ w_proj, const float* __restrict__ b_proj,
             const float* __restrict__ ln2_g, const float* __restrict__ ln2_b,
             const short* __restrict__ wf1_f, const short* __restrict__ wf2_f,
             const float* __restrict__ b_fc1, const float* __restrict__ b_fc2,
             float* __restrict__ out)
{
    __shared__ __align__(16) unsigned char lds[8192];
    const int tid = threadIdx.x, b = blockIdx.y, chunk = blockIdx.x;
    const int w = tid >> 6, l = tid & 63, l15 = l & 15, g = l >> 4;
    unsigned char* tb = lds + w * 2048;   // per-wave [16 tok][64 chan] bf16, XOR-swizzled

    // register-resident constants
    short8 Wp[4][2];
    #pragma unroll
    for (int ct = 0; ct < 4; ct++)
        #pragma unroll
        for (int ks = 0; ks < 2; ks++)
            #pragma unroll
            for (int j = 0; j < 8; j++)
                Wp[ct][ks][j] = bfs(w_proj[(ks * 32 + g * 8 + j) * 64 + ct * 16 + l15]);
    short8 Bkv[2][2][2];  // [s][h][ks]
    #pragma unroll
    for (int s = 0; s < 2; s++)
        #pragma unroll
        for (int h = 0; h < 2; h++)
            #pragma unroll
            for (int ks = 0; ks < 2; ks++)
                #pragma unroll
                for (int j = 0; j < 8; j++)
                    Bkv[s][h][ks][j] = bfs(kv_g[(size_t)b * 4096 +
                        ((size_t)(s * 2 + h) * 64 + ks * 32 + g * 8 + j) * 16 + l15]);
    float kmP[2][8], kmN[2][8], pw3[2][8];
    #pragma unroll
    for (int h = 0; h < 2; h++)
        #pragma unroll
        for (int j = 0; j < 8; j++) {
            int d = g * 8 + j;
            kmP[h][j] = km_g[b * 128 + h * 64 + d];
            kmN[h][j] = km_g[b * 128 + h * 64 + 32 + d];
            pw3[h][j] = 1.f + 4.f * sigm(power_p[h * 32 + d]);
        }
    float bpj[4], g2[4], b2[4], bfc2v[4];
    #pragma unroll
    for (int ct = 0; ct < 4; ct++) {
        int ch = l15 + 16 * ct;
        bpj[ct] = b_proj[ch]; g2[ct] = ln2_g[ch]; b2[ct] = ln2_b[ch]; bfc2v[ct] = b_fc2[ch];
    }
    float bf1v[16];
    #pragma unroll
    for (int ct = 0; ct < 16; ct++) bf1v[ct] = b_fc1[ct * 16 + l15];

    for (int it = 0; it < 4; ++it) {
        const int tok0 = chunk * 256 + (it * 4 + w) * 16;
        const size_t rowb = (size_t)b * NT + tok0;

        // ---- phase A: q features + z
        short8 Fqp[2], Fqn[2];
        float zs[2], zo[2];
        #pragma unroll
        for (int h = 0; h < 2; h++) {
            short8 q8 = *(const short8*)((const short*)qb + (rowb + l15) * 64 + h * 32 + g * 8);
            float ds_ = 0.f, do_ = 0.f;
            #pragma unroll
            for (int j = 0; j < 8; j++) {
                float q = sbf(q8[j]);
                float qp = safe_pow(q, pw3[h][j]);
                float qn = safe_pow(-q, pw3[h][j]);
                ds_ += qp * kmP[h][j] + qn * kmN[h][j];
                do_ += qn * kmP[h][j] + qp * kmN[h][j];
                Fqp[h][j] = bfs(qp); Fqn[h][j] = bfs(qn);
            }
            ds_ += __shfl_xor(ds_, 16, 64); ds_ += __shfl_xor(ds_, 32, 64);
            do_ += __shfl_xor(do_, 16, 64); do_ += __shfl_xor(do_, 32, 64);
            zs[h] = __builtin_amdgcn_rcpf(ds_ + 1e-6f);
            zo[h] = __builtin_amdgcn_rcpf(do_ + 1e-6f);
        }

        // ---- phase B: attention MFMA
        f32x4 at[4];
        #pragma unroll
        for (int hs = 0; hs < 4; hs++) { f32x4 z4 = {0.f,0.f,0.f,0.f}; at[hs] = z4; }
        #pragma unroll
        for (int h = 0; h < 2; h++) {
            at[h*2+0] = MFMA(Fqp[h], Bkv[0][h][0], at[h*2+0]);
            at[h*2+0] = MFMA(Fqn[h], Bkv[0][h][1], at[h*2+0]);
            at[h*2+1] = MFMA(Fqn[h], Bkv[1][h][0], at[h*2+1]);
            at[h*2+1] = MFMA(Fqp[h], Bkv[1][h][1], at[h*2+1]);
        }

        // ---- phase C: z-scale, transpose, + dwc, * gate
        #pragma unroll
        for (int hs = 0; hs < 4; hs++) {
            int h = hs >> 1, s = hs & 1;
            float zv = s ? zo[h] : zs[h];
            int cb = h * 32 + s * 16;
            #pragma unroll
            for (int r = 0; r < 4; r++) {
                float zz = __shfl(zv, g * 4 + r, 64);
                int tok = g * 4 + r;
                *(short*)(tb + tok * 128 + (((cb + l15) * 2) ^ ((tok & 7) << 4))) = bfs(at[hs][r] * zz);
            }
        }
        short8 Ap[2];
        #pragma unroll
        for (int ks = 0; ks < 2; ks++) {
            short8 t8 = *(short8*)(tb + l15 * 128 + ((ks * 64 + g * 16) ^ ((l15 & 7) << 4)));
            const size_t goff = (rowb + l15) * 64 + ks * 32 + g * 8;
            short8 vd8 = *(const short8*)((const short*)vdb + goff);
            short8 g8  = *(const short8*)((const short*)gbuf + goff);
            #pragma unroll
            for (int j = 0; j < 8; j++)
                Ap[ks][j] = bfs((sbf(t8[j]) + sbf(vd8[j])) * sbf(g8[j]));
        }

        // ---- phase D: proj
        f32x4 pc[4];
        #pragma unroll
        for (int ct = 0; ct < 4; ct++) {
            f32x4 z4 = {0.f,0.f,0.f,0.f};
            z4 = MFMA(Ap[0], Wp[ct][0], z4);
            pc[ct] = MFMA(Ap[1], Wp[ct][1], z4);
        }

        // ---- phase E: residual + LN2
        float xm[4][4], h2v[4][4];
        #pragma unroll
        for (int ct = 0; ct < 4; ct++)
            #pragma unroll
            for (int r = 0; r < 4; r++)
                xm[ct][r] = x[(rowb + g * 4 + r) * 64 + l15 + 16 * ct] + pc[ct][r] + bpj[ct];
        #pragma unroll
        for (int r = 0; r < 4; r++) {
            float s1 = xm[0][r] + xm[1][r] + xm[2][r] + xm[3][r];
            float s2 = xm[0][r]*xm[0][r] + xm[1][r]*xm[1][r] + xm[2][r]*xm[2][r] + xm[3][r]*xm[3][r];
            #pragma unroll
            for (int m = 1; m < 16; m <<= 1) { s1 += __shfl_xor(s1, m, 64); s2 += __shfl_xor(s2, m, 64); }
            float mu = s1 * 0.015625f;
            float var = s2 * 0.015625f - mu * mu;
            float rs = rsqrtf(var + 1e-5f);
            #pragma unroll
            for (int ct = 0; ct < 4; ct++)
                h2v[ct][r] = (xm[ct][r] - mu) * rs * g2[ct] + b2[ct];
        }

        // ---- phase F: h2 transpose
        #pragma unroll
        for (int ct = 0; ct < 4; ct++)
            #pragma unroll
            for (int r = 0; r < 4; r++) {
                int tok = g * 4 + r;
                *(short*)(tb + tok * 128 + (((ct * 16 + l15) * 2) ^ ((tok & 7) << 4))) = bfs(h2v[ct][r]);
            }
        short8 Ah[2];
        #pragma unroll
        for (int ks = 0; ks < 2; ks++)
            Ah[ks] = *(short8*)(tb + l15 * 128 + ((ks * 64 + g * 16) ^ ((l15 & 7) << 4)));

        // ---- phase G: fc1 + gelu + fc2 (chunked over 4 groups of 64 fc1-cols)
        f32x4 a2[4];
        #pragma unroll
        for (int ct = 0; ct < 4; ct++) { f32x4 z4 = {0.f,0.f,0.f,0.f}; a2[ct] = z4; }
        #pragma unroll
        for (int g4 = 0; g4 < 4; g4++) {
            f32x4 fc[4];
            #pragma unroll
            for (int ctl = 0; ctl < 4; ctl++) {
                int ct = g4 * 4 + ctl;
                short8 f0 = *(const short8*)(wf1_f + (ct * 2 + 0) * 512 + l * 8);
                short8 f1 = *(const short8*)(wf1_f + (ct * 2 + 1) * 512 + l * 8);
                f32x4 z4 = {0.f,0.f,0.f,0.f};
                z4 = MFMA(Ah[0], f0, z4);
                fc[ctl] = MFMA(Ah[1], f1, z4);
            }
            #pragma unroll
            for (int ctl = 0; ctl < 4; ctl++)
                #pragma unroll
                for (int r = 0; r < 4; r++) {
                    float mv = fc[ctl][r] + bf1v[g4 * 4 + ctl];
                    float gl = mv * __builtin_amdgcn_rcpf(1.f +
                        __builtin_amdgcn_exp2f(mv * (-2.30220825f - 0.10294385f * mv * mv)));
                    int tok = g * 4 + r;
                    *(short*)(tb + tok * 128 + (((ctl * 16 + l15) * 2) ^ ((tok & 7) << 4))) = bfs(gl);
                }
            #pragma unroll
            for (int ksl = 0; ksl < 2; ksl++) {
                short8 Ag = *(short8*)(tb + l15 * 128 + ((ksl * 64 + g * 16) ^ ((l15 & 7) << 4)));
                int ks = g4 * 2 + ksl;
                #pragma unroll
                for (int ct2 = 0; ct2 < 4; ct2++) {
                    short8 wv = *(const short8*)(wf2_f + (ct2 * 8 + ks) * 512 + l * 8);
                    a2[ct2] = MFMA(Ag, wv, a2[ct2]);
                }
            }
        }

        // ---- phase H: output
        #pragma unroll
        for (int ct = 0; ct < 4; ct++)
            #pragma unroll
            for (int r = 0; r < 4; r++)
                out[(rowb + g * 4 + r) * 64 + l15 + 16 * ct] = xm[ct][r] + a2[ct][r] + bfc2v[ct];
    }
}

// ---------------------------------------------------------------------------
extern "C" void kernel_launch(void* const* d_in, const int* in_sizes, int n_in,
                              void* d_out, int out_size, void* d_ws, size_t ws_size,
                              hipStream_t stream)
{
    const float* x       = (const float*)d_in[0];
    const float* ln1_g   = (const float*)d_in[3];
    const float* ln1_b   = (const float*)d_in[4];
    const float* w_qg    = (const float*)d_in[5];
    const float* w_kv    = (const float*)d_in[6];
    const float* pos     = (const float*)d_in[7];
    const float* scale_p = (const float*)d_in[8];
    const float* power_p = (const float*)d_in[9];
    const float* dwc_w   = (const float*)d_in[10];
    const float* dwc_b   = (const float*)d_in[11];
    const float* w_proj  = (const float*)d_in[12];
    const float* b_proj  = (const float*)d_in[13];
    const float* ln2_g   = (const float*)d_in[14];
    const float* ln2_b   = (const float*)d_in[15];
    const float* w_fc1   = (const float*)d_in[16];
    const float* b_fc1   = (const float*)d_in[17];
    const float* w_fc2   = (const float*)d_in[18];
    const float* b_fc2   = (const float*)d_in[19];
    float* out = (float*)d_out;

    // workspace layout
    size_t ntc = (size_t)NTOK * 64;
    bf16* qb   = (bf16*)d_ws;
    bf16* gbuf = qb + ntc;
    bf16* vbuf = gbuf + ntc;
    bf16* vdb  = vbuf + ntc;
    float* km_g = (float*)(vdb + ntc);               // [B][128]
    float* kv_g = km_g + (size_t)NB * 128;           // [B][4096]
    short* wqk_f = (short*)(kv_g + (size_t)NB * 4096);
    short* wf1_f = wqk_f + 16384;
    short* wf2_f = wf1_f + 16384;

    // reduction partials live in d_out (scratch before k3 overwrites it)
    float* part = (float*)d_out;  // [B][32][4][4224] = 34.6 MB < 64 MB

    k0_prep<<<dim3(192), 256, 0, stream>>>(w_qg, w_kv, w_fc1, w_fc2, wqk_f, wf1_f, wf2_f);
    k1_proj<<<dim3(32, NB), 256, 0, stream>>>(x, ln1_g, ln1_b, wqk_f, pos, scale_p, power_p,
                                              qb, gbuf, vbuf, part);
    k1b_reduce<<<dim3(17, NB), 256, 0, stream>>>(part, km_g, kv_g);
    k2_dwc<<<dim3(64, NB), 256, 0, stream>>>(vbuf, dwc_w, dwc_b, vdb);
    k3_main<<<dim3(64, NB), 256, 0, stream>>>(x, qb, gbuf, vdb, km_g, kv_g, power_p,
                                              w_proj, b_proj, ln2_g, ln2_b,
                                              wf1_f, wf2_f, b_fc1, b_fc2, out);
}